// Round 4
// baseline (374.177 us; speedup 1.0000x reference)
//
#include <hip/hip_runtime.h>

#define L 512
#define LL (512*512)
#define D 128
#define DI 64

typedef unsigned short u16;
typedef short bf8 __attribute__((ext_vector_type(8)));
typedef float f4 __attribute__((ext_vector_type(4)));

union B8 { bf8 v; u16 u[8]; uint4 q; };

__device__ inline u16 f2bf(float f) {
  unsigned u = __builtin_bit_cast(unsigned, f);
  unsigned r = (u + 0x7FFFu + ((u >> 16) & 1u)) >> 16;
  return (u16)r;
}

// ---------------- K1: g1/g2 projection, transposed channel-major outputs ----
// grid 1024 (32x32 spatial tiles of 16x16), 512 threads (8 waves)
__global__ __launch_bounds__(512)
void k1(const float* __restrict__ pair, const float* __restrict__ Wg1,
        const float* __restrict__ bg1, const float* __restrict__ Wg2,
        const float* __restrict__ bg2, u16* __restrict__ g1t, u16* __restrict__ g2t)
{
  __shared__ u16 WL[128*128];   // W^T [n][k], XOR-swizzled, 32KB
  __shared__ u16 OL[64*256];    // output staging, one 64-ch half at a time, 32KB
  const int tid = threadIdx.x;
  const int w = tid >> 6, lane = tid & 63;
  const int llo = lane & 15, lhi = lane >> 4;
  const int bx = blockIdx.x;
  const int i0 = (bx >> 5) << 4;
  const int c0 = (bx & 31) << 4;

  // stage W = [Wg1 | Wg2] as WL[n][k] bf16, swizzle: elem k ^= (n&7)<<3
  {
    const int n = tid >> 2;           // 0..127
    const int kb = (tid & 3) << 5;    // 0,32,64,96
    const float* src = (n < 64) ? (Wg1 + n) : (Wg2 + (n - 64));
    const int xr = (n & 7) << 3;
    for (int q = 0; q < 32; ++q) {
      int k = kb + q;
      WL[n*128 + (k ^ xr)] = f2bf(src[(size_t)k * 64]);
    }
  }
  __syncthreads();

  f4 acc[2][8];
  #pragma unroll
  for (int a = 0; a < 2; ++a)
    #pragma unroll
    for (int b = 0; b < 8; ++b) acc[a][b] = (f4){0.f,0.f,0.f,0.f};

  #pragma unroll
  for (int ks = 0; ks < 4; ++ks) {
    B8 bfr[8];
    const int kel = ks*32 + lhi*8;
    #pragma unroll
    for (int nf = 0; nf < 8; ++nf) {
      int n = nf*16 + llo;
      bfr[nf].q = *(const uint4*)&WL[n*128 + (kel ^ ((n & 7) << 3))];
    }
    #pragma unroll
    for (int mf = 0; mf < 2; ++mf) {
      int r = w*2 + mf;
      const float* ap = pair + (size_t)((i0 + r)*L + c0 + llo)*D + kel;
      float4 a0 = *(const float4*)ap;
      float4 a1 = *(const float4*)(ap + 4);
      B8 av;
      av.u[0]=f2bf(a0.x); av.u[1]=f2bf(a0.y); av.u[2]=f2bf(a0.z); av.u[3]=f2bf(a0.w);
      av.u[4]=f2bf(a1.x); av.u[5]=f2bf(a1.y); av.u[6]=f2bf(a1.z); av.u[7]=f2bf(a1.w);
      #pragma unroll
      for (int nf = 0; nf < 8; ++nf)
        acc[mf][nf] = __builtin_amdgcn_mfma_f32_16x16x32_bf16(av.v, bfr[nf].v, acc[mf][nf], 0, 0, 0);
    }
  }

  float bias[8];
  #pragma unroll
  for (int nf = 0; nf < 8; ++nf) {
    int n = nf*16 + llo;
    bias[nf] = (n < 64) ? bg1[n] : bg2[n - 64];
  }

  // two halves: h=0 -> g1 (ch 0..63, pos = r*16+c), h=1 -> g2 (pos = c*16+r)
  #pragma unroll
  for (int h = 0; h < 2; ++h) {
    __syncthreads();
    #pragma unroll
    for (int nf4 = 0; nf4 < 4; ++nf4) {
      const int nf = h*4 + nf4;
      const int chl = nf*16 + llo - h*64;  // 0..63
      const int xr = (chl & 7) << 2;
      #pragma unroll
      for (int mf = 0; mf < 2; ++mf) {
        const int r = w*2 + mf;
        const int cb = lhi*4;
        union { u16 h4[4]; uint2 d2; } vb;
        #pragma unroll
        for (int e = 0; e < 4; ++e) vb.h4[e] = f2bf(acc[mf][nf][e] + bias[nf]);
        if (h == 0) {
          int p = (r*16 + cb) ^ xr;
          *(uint2*)&OL[chl*256 + p] = vb.d2;
        } else {
          #pragma unroll
          for (int e = 0; e < 4; ++e)
            OL[chl*256 + (((cb + e)*16 + r) ^ xr)] = vb.h4[e];
        }
      }
    }
    __syncthreads();
    u16* dst0 = (h == 0) ? g1t : g2t;
    #pragma unroll
    for (int t2 = 0; t2 < 2; ++t2) {
      const int q = tid*2 + t2;
      const int chl = q >> 4;   // 0..63
      const int li = q & 15;    // line within tile
      const int xr = (chl & 7) << 2;
      union { u16 h4[16]; uint4 q4[2]; uint2 d2[4]; } tb;
      #pragma unroll
      for (int s = 0; s < 4; ++s) {
        int p = (li*16 + s*4) ^ xr;
        tb.d2[s] = *(const uint2*)&OL[chl*256 + p];
      }
      size_t off = (h == 0)
        ? ((size_t)chl*LL + (size_t)(i0 + li)*L + (size_t)c0)
        : ((size_t)chl*LL + (size_t)(c0 + li)*L + (size_t)i0);
      *(uint4*)(dst0 + off)     = tb.q4[0];
      *(uint4*)(dst0 + off + 8) = tb.q4[1];
    }
  }
}

// ---------------- K2: per-channel 512x512x512 bf16 GEMM, C = A * Y^T --------
// grid 1024 (64 d x 4 x 4), 256 threads (4 waves), 128x128 tile, BK=64
__global__ __launch_bounds__(256)
void k2(const u16* __restrict__ g1t, const u16* __restrict__ g2t, u16* __restrict__ pt)
{
  __shared__ u16 SM[128*128];  // 32KB: A tile [0,8192), Y tile [8192,16384); C reuses all
  const int tid = threadIdx.x;
  const int lane = tid & 63, w = tid >> 6;
  const int llo = lane & 15, lhi = lane >> 4;
  const int bx = blockIdx.x;
  const int wg = ((bx & 7) << 7) | (bx >> 3);  // XCD-contiguous remap (bijective, 1024 = 8*128)
  const int d  = wg >> 4;
  const int i0 = ((wg >> 2) & 3) << 7;
  const int j0 = (wg & 3) << 7;

  const u16* Ag = g1t + (size_t)d*LL;
  const u16* Yg = g2t + (size_t)d*LL;

  f4 acc[4][4];
  #pragma unroll
  for (int a = 0; a < 4; ++a)
    #pragma unroll
    for (int b = 0; b < 4; ++b) acc[a][b] = (f4){0.f,0.f,0.f,0.f};

  const int wr = (w >> 1) * 64, wc = (w & 1) * 64;

  const int srow = tid & 127;
  const u16* sg = (tid < 128) ? (Ag + (size_t)(i0 + srow)*L) : (Yg + (size_t)(j0 + srow)*L);
  u16* sl = (tid < 128) ? SM : (SM + 8192);
  const int sx = (srow & 7) << 3;

  for (int kt = 0; kt < 8; ++kt) {
    const int k0 = kt*64;
    #pragma unroll
    for (int q = 0; q < 8; ++q) {
      uint4 vv = *(const uint4*)(sg + k0 + q*8);
      *(uint4*)&sl[srow*64 + ((q*8) ^ sx)] = vv;
    }
    __syncthreads();
    #pragma unroll
    for (int ks = 0; ks < 2; ++ks) {
      B8 af[4], yf[4];
      const int kel = ks*32 + lhi*8;
      #pragma unroll
      for (int f = 0; f < 4; ++f) {
        int ra = wr + f*16 + llo;
        af[f].q = *(const uint4*)&SM[ra*64 + (kel ^ ((ra & 7) << 3))];
        int ry = wc + f*16 + llo;
        yf[f].q = *(const uint4*)&SM[8192 + ry*64 + (kel ^ ((ry & 7) << 3))];
      }
      #pragma unroll
      for (int mf = 0; mf < 4; ++mf)
        #pragma unroll
        for (int nf = 0; nf < 4; ++nf)
          acc[mf][nf] = __builtin_amdgcn_mfma_f32_16x16x32_bf16(af[mf].v, yf[nf].v, acc[mf][nf], 0, 0, 0);
    }
    __syncthreads();
  }

  // stage C (bf16) into SM [128 i][128 j] swizzled, then write rows
  #pragma unroll
  for (int mf = 0; mf < 4; ++mf) {
    #pragma unroll
    for (int nf = 0; nf < 4; ++nf) {
      const int jj = wc + nf*16 + llo;
      #pragma unroll
      for (int e = 0; e < 4; ++e) {
        const int ii = wr + mf*16 + lhi*4 + e;
        SM[ii*128 + (jj ^ ((ii & 7) << 3))] = f2bf(acc[mf][nf][e]);
      }
    }
  }
  __syncthreads();
  {
    const int ii = tid >> 1;
    const int half = (tid & 1) << 6;
    u16* dst = pt + (size_t)d*LL + (size_t)(i0 + ii)*L + j0 + half;
    const int xr = (ii & 7) << 3;
    #pragma unroll
    for (int q = 0; q < 8; ++q)
      *(uint4*)(dst + q*8) = *(const uint4*)&SM[ii*128 + ((half + q*8) ^ xr)];
  }
}

// ---------------- K3: proj @ Wp + bias + mask + residual + LayerNorm --------
// grid 2048 (512 i x 4 j-tiles of 128), 256 threads (4 waves)
__global__ __launch_bounds__(256)
void k3(const u16* __restrict__ pt, const float* __restrict__ pair,
        const float* __restrict__ mask, const float* __restrict__ Wp,
        const float* __restrict__ bp, const float* __restrict__ gamma,
        const float* __restrict__ beta, float* __restrict__ out)
{
  __shared__ u16 PL[128*64];   // P tile [pos][d], swizzled, 16KB
  __shared__ u16 WT[128*64];   // Wp^T [n][d], swizzled, 16KB
  __shared__ float MS[128];
  const int tid = threadIdx.x;
  const int lane = tid & 63, w = tid >> 6;
  const int llo = lane & 15, lhi = lane >> 4;
  const int bx = blockIdx.x;
  const int i  = bx >> 2;
  const int j0 = (bx & 3) << 7;

  // stage Wp^T
  {
    const int n = tid >> 1;
    const int dh = (tid & 1) << 5;
    const int xr = (n & 7) << 3;
    for (int q = 0; q < 32; ++q) {
      int dd = dh + q;
      WT[n*64 + (dd ^ xr)] = f2bf(Wp[(size_t)dd*128 + n]);
    }
  }
  if (tid < 128) MS[tid] = mask[(size_t)i*L + j0 + tid];
  // stage P tile: thread -> channel d = tid>>2, 4 chunks of 8 j
  {
    const int dd = tid >> 2;
    const u16* src = pt + (size_t)dd*LL + (size_t)i*L + j0;
    #pragma unroll
    for (int c = 0; c < 4; ++c) {
      const int jl = ((tid & 3)*4 + c) * 8;
      uint4 vv = *(const uint4*)(src + jl);
      const u16* pv = (const u16*)&vv;
      #pragma unroll
      for (int e = 0; e < 8; ++e) {
        int p = jl + e;
        PL[p*64 + (dd ^ ((p & 7) << 3))] = pv[e];
      }
    }
  }
  __syncthreads();

  f4 acc[2][8];
  #pragma unroll
  for (int a = 0; a < 2; ++a)
    #pragma unroll
    for (int b = 0; b < 8; ++b) acc[a][b] = (f4){0.f,0.f,0.f,0.f};

  #pragma unroll
  for (int ks = 0; ks < 2; ++ks) {
    const int kel = ks*32 + lhi*8;
    B8 bf[8];
    #pragma unroll
    for (int nf = 0; nf < 8; ++nf) {
      int n = nf*16 + llo;
      bf[nf].q = *(const uint4*)&WT[n*64 + (kel ^ ((n & 7) << 3))];
    }
    #pragma unroll
    for (int mf = 0; mf < 2; ++mf) {
      int p = w*32 + mf*16 + llo;
      B8 av;
      av.q = *(const uint4*)&PL[p*64 + (kel ^ ((p & 7) << 3))];
      #pragma unroll
      for (int nf = 0; nf < 8; ++nf)
        acc[mf][nf] = __builtin_amdgcn_mfma_f32_16x16x32_bf16(av.v, bf[nf].v, acc[mf][nf], 0, 0, 0);
    }
  }

  float bpv[8], gv[8], bv[8];
  #pragma unroll
  for (int nf = 0; nf < 8; ++nf) {
    int n = nf*16 + llo;
    bpv[nf] = bp[n]; gv[nf] = gamma[n]; bv[nf] = beta[n];
  }

  const size_t rowbase = (size_t)i*L + j0;
  #pragma unroll
  for (int mf = 0; mf < 2; ++mf) {
    #pragma unroll
    for (int e = 0; e < 4; ++e) {
      const int pl = w*32 + mf*16 + lhi*4 + e;
      const float mk = MS[pl];
      const float* prow = pair + (rowbase + pl)*D;
      float xv[8];
      float s1 = 0.f, s2 = 0.f;
      #pragma unroll
      for (int nf = 0; nf < 8; ++nf) {
        int n = nf*16 + llo;
        float x = prow[n] + mk*acc[mf][nf][e] + bpv[nf];
        xv[nf] = x; s1 += x; s2 += x*x;
      }
      #pragma unroll
      for (int m = 1; m < 16; m <<= 1) {
        s1 += __shfl_xor(s1, m);
        s2 += __shfl_xor(s2, m);
      }
      const float mu = s1 * (1.0f/128.0f);
      const float var = s2 * (1.0f/128.0f) - mu*mu;
      const float rs = rsqrtf(var + 1e-5f);
      float* orow = out + (rowbase + pl)*D;
      #pragma unroll
      for (int nf = 0; nf < 8; ++nf) {
        int n = nf*16 + llo;
        orow[n] = (xv[nf] - mu)*rs*gv[nf] + bv[nf];
      }
    }
  }
}

extern "C" void kernel_launch(void* const* d_in, const int* in_sizes, int n_in,
                              void* d_out, int out_size, void* d_ws, size_t ws_size,
                              hipStream_t stream) {
  (void)in_sizes; (void)n_in; (void)out_size; (void)ws_size;
  const float* pair = (const float*)d_in[0];
  const float* mask = (const float*)d_in[1];
  const float* Wg1  = (const float*)d_in[2];
  const float* bg1  = (const float*)d_in[3];
  const float* Wg2  = (const float*)d_in[4];
  const float* bg2  = (const float*)d_in[5];
  const float* Wp   = (const float*)d_in[6];
  const float* bp   = (const float*)d_in[7];
  const float* gamma= (const float*)d_in[8];
  const float* beta = (const float*)d_in[9];
  float* out = (float*)d_out;

  u16* g1t = (u16*)d_ws;                     // 64*512*512 bf16 = 33.5MB
  u16* g2t = g1t + (size_t)DI*LL;            // 33.5MB
  u16* pt  = g2t + (size_t)DI*LL;            // 33.5MB

  hipLaunchKernelGGL(k1, dim3(1024), dim3(512), 0, stream,
                     pair, Wg1, bg1, Wg2, bg2, g1t, g2t);
  hipLaunchKernelGGL(k2, dim3(1024), dim3(256), 0, stream, g1t, g2t, pt);
  hipLaunchKernelGGL(k3, dim3(2048), dim3(256), 0, stream,
                     pt, pair, mask, Wp, bp, gamma, beta, out);
}